// Round 1
// baseline (176.084 us; speedup 1.0000x reference)
//
#include <hip/hip_runtime.h>
#include <hip/hip_bf16.h>

#define TT 512
#define BB 64
#define KK 10
#define DD 1024

// ---------------- Kernel 1: emissions = wf @ W + b -------------------------
// grid 512 blocks x 256 threads; each block computes 64 rows; wave = 1 row/iter.
__global__ __launch_bounds__(256) void k_emissions(
    const float* __restrict__ wf, const float* __restrict__ W,
    const float* __restrict__ bias, float* __restrict__ em, float* loss_slot) {
    __shared__ float Wt[KK][DD];  // 40 KB, W transposed
    for (int idx = threadIdx.x; idx < DD * KK; idx += 256) {
        int d = idx / KK, k = idx % KK;
        Wt[k][d] = W[idx];
    }
    __syncthreads();
    if (blockIdx.x == 0 && threadIdx.x == 0) *loss_slot = 0.f;  // init loss accum

    const int wave = threadIdx.x >> 6;
    const int lane = threadIdx.x & 63;

    float bk[KK];
    #pragma unroll
    for (int k = 0; k < KK; ++k) bk[k] = bias[k];

    for (int r = 0; r < 16; ++r) {
        const int row = blockIdx.x * 64 + wave * 16 + r;
        float acc[KK];
        #pragma unroll
        for (int k = 0; k < KK; ++k) acc[k] = 0.f;
        #pragma unroll
        for (int c = 0; c < 4; ++c) {
            const int d0 = c * 256 + lane * 4;
            const float4 f = *reinterpret_cast<const float4*>(wf + (size_t)row * DD + d0);
            #pragma unroll
            for (int k = 0; k < KK; ++k) {
                const float4 w = *reinterpret_cast<const float4*>(&Wt[k][d0]);
                acc[k] += f.x * w.x + f.y * w.y + f.z * w.z + f.w * w.w;
            }
        }
        #pragma unroll
        for (int off = 32; off >= 1; off >>= 1) {
            #pragma unroll
            for (int k = 0; k < KK; ++k) acc[k] += __shfl_xor(acc[k], off);
        }
        if (lane == 0) {
            #pragma unroll
            for (int k = 0; k < KK; ++k) em[(size_t)row * KK + k] = acc[k] + bk[k];
        }
    }
}

// ---------------- Kernel 2: CRF scans --------------------------------------
// 128 blocks x 64 threads. blocks 0..63: Viterbi+backtrace for batch b.
// blocks 64..127: LSE forward + numerator, atomicAdd(denom - numer).
__global__ __launch_bounds__(64) void k_scan(
    const int* __restrict__ words, const int* __restrict__ tags,
    const float* __restrict__ em, const float* __restrict__ startv,
    const float* __restrict__ endv, const float* __restrict__ trans,
    int* __restrict__ paths, float* __restrict__ loss_slot) {
    __shared__ unsigned char hist[TT][16];  // 8 KB backpointers (viterbi only)

    const int b = blockIdx.x & 63;
    const bool do_viterbi = blockIdx.x < 64;
    const int lane = threadIdx.x;
    const int j = lane;  // state owned by this lane (j<10 meaningful)

    // sequence length (mask is contiguous from t=0)
    int cnt = 0;
    for (int t = lane; t < TT; t += 64) cnt += (words[t * BB + b] != 0) ? 1 : 0;
    #pragma unroll
    for (int off = 32; off >= 1; off >>= 1) cnt += __shfl_xor(cnt, off);
    const int len = cnt;

    // transition column for my state j: trcol[i] = trans[i][j]
    float trcol[KK];
    #pragma unroll
    for (int i = 0; i < KK; ++i) trcol[i] = 0.f;
    if (j < KK) {
        #pragma unroll
        for (int i = 0; i < KK; ++i) trcol[i] = trans[i * KK + j];
    }

    // initial scores, replicated in every lane
    float s[KK];
    #pragma unroll
    for (int i = 0; i < KK; ++i) s[i] = startv[i] + em[(size_t)b * KK + i];

    if (do_viterbi) {
        float emj_next = (j < KK && len > 1) ? em[((size_t)1 * BB + b) * KK + j] : 0.f;
        for (int t = 1; t < len; ++t) {
            const float emj = emj_next;
            if (t + 1 < len && j < KK) emj_next = em[((size_t)(t + 1) * BB + b) * KK + j];
            float best = s[0] + trcol[0];
            int bi = 0;
            #pragma unroll
            for (int i = 1; i < KK; ++i) {
                const float v = s[i] + trcol[i];
                if (v > best) { best = v; bi = i; }  // strict > keeps first max (jnp tie-break)
            }
            const float snew = best + emj;
            if (j < KK) hist[t][j] = (unsigned char)bi;
            #pragma unroll
            for (int i = 0; i < KK; ++i) s[i] = __shfl(snew, i);
        }
        // last tag = argmax(s + end), first-index tie-break
        float bestf = s[0] + endv[0];
        int last = 0;
        #pragma unroll
        for (int i = 1; i < KK; ++i) {
            const float v = s[i] + endv[i];
            if (v > bestf) { bestf = v; last = i; }
        }
        // zero the padded tail in parallel
        for (int t = len + lane; t < TT; t += 64) paths[t * BB + b] = 0;
        __syncthreads();  // make hist writes visible for the serial chase
        if (lane == 0) {
            int cur = last;
            paths[(len - 1) * BB + b] = cur;
            for (int t = len - 1; t >= 1; --t) {
                cur = hist[t][cur];
                paths[(t - 1) * BB + b] = cur;
            }
        }
    } else {
        // ---- numerator: gold path score ----
        float part = 0.f;
        for (int t = 1 + lane; t < len; t += 64) {
            const int tp = tags[(t - 1) * BB + b];
            const int tc = tags[t * BB + b];
            part += trans[tp * KK + tc] + em[((size_t)t * BB + b) * KK + tc];
        }
        #pragma unroll
        for (int off = 32; off >= 1; off >>= 1) part += __shfl_xor(part, off);
        const int t0 = tags[b];                  // tags[0][b]
        const int te = tags[(len - 1) * BB + b]; // tag at seq end
        const float numer = part + startv[t0] + em[(size_t)b * KK + t0] + endv[te];

        // ---- denominator: forward algorithm ----
        float emj_next = (j < KK && len > 1) ? em[((size_t)1 * BB + b) * KK + j] : 0.f;
        for (int t = 1; t < len; ++t) {
            const float emj = emj_next;
            if (t + 1 < len && j < KK) emj_next = em[((size_t)(t + 1) * BB + b) * KK + j];
            float m = s[0] + trcol[0];
            #pragma unroll
            for (int i = 1; i < KK; ++i) m = fmaxf(m, s[i] + trcol[i]);
            float sum = 0.f;
            #pragma unroll
            for (int i = 0; i < KK; ++i) sum += __expf(s[i] + trcol[i] - m);
            const float snew = m + __logf(sum) + emj;
            #pragma unroll
            for (int i = 0; i < KK; ++i) s[i] = __shfl(snew, i);
        }
        float m = s[0] + endv[0];
        #pragma unroll
        for (int i = 1; i < KK; ++i) m = fmaxf(m, s[i] + endv[i]);
        float sum = 0.f;
        #pragma unroll
        for (int i = 0; i < KK; ++i) sum += __expf(s[i] + endv[i] - m);
        const float denom = m + __logf(sum);
        if (lane == 0) atomicAdd(loss_slot, denom - numer);
    }
}

extern "C" void kernel_launch(void* const* d_in, const int* in_sizes, int n_in,
                              void* d_out, int out_size, void* d_ws, size_t ws_size,
                              hipStream_t stream) {
    const int*   words  = (const int*)d_in[0];
    const int*   tags   = (const int*)d_in[1];
    const float* wf     = (const float*)d_in[2];
    const float* W      = (const float*)d_in[3];
    const float* bias   = (const float*)d_in[4];
    const float* startv = (const float*)d_in[5];
    const float* endv   = (const float*)d_in[6];
    const float* trans  = (const float*)d_in[7];

    float* em        = (float*)d_ws;                 // T*B*K floats = 1.31 MB
    int*   paths     = (int*)d_out;                  // paths as int32 VALUES
    float* loss_slot = ((float*)d_out) + TT * BB;    // loss as float32 bits

    k_emissions<<<512, 256, 0, stream>>>(wf, W, bias, em, loss_slot);
    k_scan<<<128, 64, 0, stream>>>(words, tags, em, startv, endv, trans, paths, loss_slot);
}

// Round 2
// 121.051 us; speedup vs baseline: 1.4546x; 1.4546x over previous
//
#include <hip/hip_runtime.h>
#include <hip/hip_bf16.h>

#define TT 512
#define BB 64
#define KK 10
#define DD 1024
#define CL 32   // chunk length (steps per chunk)
#define NC 16   // number of chunks

typedef unsigned char uchar;

__device__ __forceinline__ float max10(const float* r) {
    float m0 = fmaxf(r[0], r[1]), m1 = fmaxf(r[2], r[3]);
    float m2 = fmaxf(r[4], r[5]), m3 = fmaxf(r[6], r[7]);
    float m4 = fmaxf(r[8], r[9]);
    m0 = fmaxf(m0, m1); m2 = fmaxf(m2, m3); m0 = fmaxf(m0, m2);
    return fmaxf(m0, m4);
}

__device__ __forceinline__ float lse10(const float* r) {
    const float m = max10(r);
    float s0 = __expf(r[0] - m) + __expf(r[1] - m);
    float s1 = __expf(r[2] - m) + __expf(r[3] - m);
    float s2 = __expf(r[4] - m) + __expf(r[5] - m);
    float s3 = __expf(r[6] - m) + __expf(r[7] - m);
    float s4 = __expf(r[8] - m) + __expf(r[9] - m);
    return m + __logf(((s0 + s1) + (s2 + s3)) + s4);
}

// ---------------- Kernel A: emissions + lengths -----------------------------
// blocks 0..511: 64 rows each (4 waves x 16 rows, 4-row register reuse of W).
// block 512: lengths per batch + zero loss slot.
__global__ __launch_bounds__(256) void k_emissions(
    const int* __restrict__ words, const float* __restrict__ wf,
    const float* __restrict__ W, const float* __restrict__ bias,
    float* __restrict__ em, int* __restrict__ lenArr, float* loss_slot) {
    const int tid = threadIdx.x;
    if (blockIdx.x == 512) {
        __shared__ int cnt[4][64];
        const int b = tid & 63, seg = tid >> 6;
        int c = 0;
        for (int t = seg; t < TT; t += 4) c += (words[t * BB + b] != 0) ? 1 : 0;
        cnt[seg][b] = c;
        __syncthreads();
        if (tid < 64) lenArr[tid] = cnt[0][tid] + cnt[1][tid] + cnt[2][tid] + cnt[3][tid];
        if (tid == 0) *loss_slot = 0.f;
        return;
    }
    __shared__ float Wt[KK][DD];  // 40 KB, W transposed
    for (int idx = tid; idx < DD * KK; idx += 256) {
        int d = idx / KK, k = idx % KK;
        Wt[k][d] = W[idx];
    }
    __syncthreads();
    const int wave = tid >> 6, lane = tid & 63;
    float bk[KK];
    #pragma unroll
    for (int k = 0; k < KK; ++k) bk[k] = bias[k];

    #pragma unroll
    for (int g = 0; g < 4; ++g) {
        const int r0 = blockIdx.x * 64 + wave * 16 + g * 4;
        float acc[4][KK];
        #pragma unroll
        for (int r = 0; r < 4; ++r)
            #pragma unroll
            for (int k = 0; k < KK; ++k) acc[r][k] = 0.f;
        #pragma unroll
        for (int it = 0; it < 4; ++it) {
            const int d0 = it * 256 + lane * 4;
            float4 w4[KK];
            #pragma unroll
            for (int k = 0; k < KK; ++k) w4[k] = *reinterpret_cast<const float4*>(&Wt[k][d0]);
            #pragma unroll
            for (int r = 0; r < 4; ++r) {
                const float4 f = *reinterpret_cast<const float4*>(wf + (size_t)(r0 + r) * DD + d0);
                #pragma unroll
                for (int k = 0; k < KK; ++k)
                    acc[r][k] += f.x * w4[k].x + f.y * w4[k].y + f.z * w4[k].z + f.w * w4[k].w;
            }
        }
        #pragma unroll
        for (int off = 32; off >= 1; off >>= 1)
            #pragma unroll
            for (int r = 0; r < 4; ++r)
                #pragma unroll
                for (int k = 0; k < KK; ++k) acc[r][k] += __shfl_xor(acc[r][k], off);
        if (lane == 0) {
            #pragma unroll
            for (int r = 0; r < 4; ++r)
                #pragma unroll
                for (int k = 0; k < KK; ++k)
                    em[(size_t)(r0 + r) * KK + k] = acc[r][k] + bk[k];
        }
    }
}

// ---------------- Kernel B: per-chunk 10x10 transfer matrices ---------------
// grid 2048: blockIdx = sem*1024 + b*16 + c; 128 threads, (i,j) = tid/10,tid%10.
// Chunk c covers steps s in [32c+1, min(32c+32, len-1)].
__global__ __launch_bounds__(128) void k_chunk(
    const float* __restrict__ em, const float* __restrict__ trans,
    const int* __restrict__ lenArr, float* __restrict__ Mlse, float* __restrict__ Mmax) {
    int id = blockIdx.x;
    const bool mx = id >= 1024; id &= 1023;
    const int b = id >> 4, c = id & 15;
    const int len = lenArr[b];
    const int s_lo = c * CL + 1;
    const int s_hi = min(c * CL + CL, len - 1);
    const int ns = s_hi - s_lo + 1;
    if (ns <= 0) return;  // identity chunk: consumers skip it

    __shared__ float Ms[KK][12];
    __shared__ float eml[CL][KK];
    const int tid = threadIdx.x;
    for (int idx = tid; idx < CL * KK; idx += 128) {
        const int sl = idx / KK, j = idx % KK;
        const int s = s_lo + sl;
        eml[sl][j] = (s <= TT - 1) ? em[((size_t)s * BB + b) * KK + j] : 0.f;
    }
    const int i = tid / KK, j = tid % KK;
    const bool act = tid < KK * KK;
    float trc[KK];
    if (act) {
        #pragma unroll
        for (int k = 0; k < KK; ++k) trc[k] = trans[k * KK + j];
    }
    __syncthreads();
    float cur = 0.f;
    if (act) { cur = trans[i * KK + j] + eml[0][j]; Ms[i][j] = cur; }
    __syncthreads();
    for (int sl = 1; sl < ns; ++sl) {
        float row[KK];
        if (act) {
            #pragma unroll
            for (int k = 0; k < KK; ++k) row[k] = Ms[i][k] + trc[k];
        }
        __syncthreads();
        if (act) {
            cur = (mx ? max10(row) : lse10(row)) + eml[sl][j];
            Ms[i][j] = cur;
        }
        __syncthreads();
    }
    if (act) {
        float* out = mx ? Mmax : Mlse;
        out[((size_t)b * NC + c) * 100 + i * KK + j] = cur;
    }
}

// ---------------- Kernel C: fold chunks per batch ---------------------------
// grid 128 x 64: blocks 0..63 = LSE (loss), 64..127 = max-plus (boundaries+last_tag)
__global__ __launch_bounds__(64) void k_fold(
    const int* __restrict__ tags, const float* __restrict__ em,
    const float* __restrict__ startv, const float* __restrict__ endv,
    const float* __restrict__ trans, const int* __restrict__ lenArr,
    const float* __restrict__ Mlse, const float* __restrict__ Mmax,
    float* __restrict__ ubnd, int* __restrict__ ltag, float* loss_slot) {
    const int b = blockIdx.x & 63;
    const bool mx = blockIdx.x >= 64;
    const int lane = threadIdx.x;
    const int len = lenArr[b];

    float v[KK];
    #pragma unroll
    for (int i = 0; i < KK; ++i) v[i] = startv[i] + em[(size_t)b * KK + i];

    const float* M = mx ? Mmax : Mlse;
    for (int c = 0; c < NC; ++c) {
        if (mx && lane < KK) ubnd[((size_t)b * NC + c) * KK + lane] = v[lane];
        const int s_lo = c * CL + 1;
        const int s_hi = min(c * CL + CL, len - 1);
        if (s_hi >= s_lo) {
            float nv = 0.f;
            if (lane < KK) {
                float r[KK];
                #pragma unroll
                for (int k = 0; k < KK; ++k)
                    r[k] = v[k] + M[((size_t)b * NC + c) * 100 + k * KK + lane];
                nv = mx ? max10(r) : lse10(r);
            }
            #pragma unroll
            for (int i = 0; i < KK; ++i) v[i] = __shfl(nv, i);
        }
    }

    if (mx) {
        // last_tag = argmax(v + end), first-index tie-break
        float best = v[0] + endv[0];
        int bi = 0;
        #pragma unroll
        for (int i = 1; i < KK; ++i) {
            const float x = v[i] + endv[i];
            if (x > best) { best = x; bi = i; }
        }
        if (lane == 0) ltag[b] = bi;
    } else {
        float r[KK];
        #pragma unroll
        for (int i = 0; i < KK; ++i) r[i] = v[i] + endv[i];
        const float denom = lse10(r);
        // numerator (gold path)
        float part = 0.f;
        for (int t = 1 + lane; t < len; t += 64) {
            const int tp = tags[(t - 1) * BB + b];
            const int tc = tags[t * BB + b];
            part += trans[tp * KK + tc] + em[((size_t)t * BB + b) * KK + tc];
        }
        #pragma unroll
        for (int off = 32; off >= 1; off >>= 1) part += __shfl_xor(part, off);
        const int t0 = tags[b];
        const int te = tags[(len - 1) * BB + b];
        const float numer = part + startv[t0] + em[(size_t)b * KK + t0] + endv[te];
        if (lane == 0) atomicAdd(loss_slot, denom - numer);
    }
}

// ---------------- Kernel D: per-chunk Viterbi re-run + backtrace map --------
// grid 1024: (b, c); 64 threads; lane j owns state j.
__global__ __launch_bounds__(64) void k_hist(
    const float* __restrict__ em, const float* __restrict__ trans,
    const int* __restrict__ lenArr, const float* __restrict__ ubnd,
    int* __restrict__ Fmap, uchar* __restrict__ hist) {
    const int b = blockIdx.x >> 4, c = blockIdx.x & 15;
    const int len = lenArr[b];
    const int s_lo = c * CL + 1;
    const int s_hi = min(c * CL + CL, len - 1);
    const int ns = s_hi - s_lo + 1;
    if (ns <= 0) return;  // identity chunk

    __shared__ float eml[CL][KK];
    __shared__ uchar hl[CL * KK];
    const int lane = threadIdx.x, j = lane;
    for (int idx = lane; idx < CL * KK; idx += 64) {
        const int sl = idx / KK, jj = idx % KK;
        const int s = s_lo + sl;
        eml[sl][jj] = (s <= TT - 1) ? em[((size_t)s * BB + b) * KK + jj] : 0.f;
    }
    float trc[KK];
    if (j < KK) {
        #pragma unroll
        for (int i = 0; i < KK; ++i) trc[i] = trans[i * KK + j];
    }
    float s[KK];
    #pragma unroll
    for (int i = 0; i < KK; ++i) s[i] = ubnd[((size_t)b * NC + c) * KK + i];
    __syncthreads();

    for (int sl = 0; sl < ns; ++sl) {
        float best = s[0] + trc[0];
        int bi = 0;
        #pragma unroll
        for (int i = 1; i < KK; ++i) {
            const float x = s[i] + trc[i];
            if (x > best) { best = x; bi = i; }
        }
        const float snew = best + eml[sl][j];
        if (j < KK) hl[sl * KK + j] = (uchar)bi;
        #pragma unroll
        for (int i = 0; i < KK; ++i) s[i] = __shfl(snew, i);
    }
    __syncthreads();
    // F_c(j): compose backpointers within the chunk (maps path[s_hi] -> path[32c])
    if (j < KK) {
        int cur = j;
        for (int sl = ns - 1; sl >= 0; --sl) cur = hl[sl * KK + cur];
        Fmap[((size_t)b * NC + c) * KK + j] = cur;
    }
    __syncthreads();
    const int* hli = (const int*)&hl[0];
    int* hg = (int*)(hist + ((size_t)b * NC + c) * (CL * KK));
    for (int idx = lane; idx < CL * KK / 4; idx += 64) hg[idx] = hli[idx];
}

// ---------------- Kernel E: boundary-tag fold + parallel path emit ----------
// grid 64 (per b) x 1024 threads (16 waves; wave w emits chunk w's path slice)
__global__ __launch_bounds__(1024) void k_paths(
    const int* __restrict__ lenArr, const int* __restrict__ ltag,
    const int* __restrict__ Fmap, const uchar* __restrict__ hist,
    int* __restrict__ paths) {
    const int b = blockIdx.x;
    const int len = lenArr[b];
    const int tid = threadIdx.x;
    __shared__ int Fl[NC][KK];
    __shared__ uchar hl[NC][CL * KK];
    __shared__ int vt[NC + 1];

    for (int idx = tid; idx < NC * KK; idx += 1024)
        Fl[idx / KK][idx % KK] = Fmap[(size_t)b * NC * KK + idx];
    const int* hg = (const int*)(hist + (size_t)b * NC * CL * KK);
    int* hls = (int*)&hl[0][0];
    for (int idx = tid; idx < NC * CL * KK / 4; idx += 1024) hls[idx] = hg[idx];
    __syncthreads();

    if (tid == 0) {
        int cur = ltag[b];
        vt[NC] = cur;
        for (int c = NC - 1; c >= 0; --c) {
            const int s_lo = c * CL + 1;
            const int s_hi = min(c * CL + CL, len - 1);
            if (s_hi >= s_lo) cur = Fl[c][cur];
            vt[c] = cur;
        }
    }
    __syncthreads();

    const int w = tid >> 6, lane = tid & 63;
    const int t0 = w * CL;
    if (lane < CL) {
        const int t = t0 + lane;
        if (t >= len) paths[t * BB + b] = 0;
    }
    if (lane == 0) {
        const int a = min(t0 + CL, len - 1);
        if (a >= t0) {
            int cur = vt[w + 1];  // = path[a]
            for (int t = a; t >= t0; --t) {
                if (t <= t0 + CL - 1) paths[t * BB + b] = cur;
                if (t > t0) cur = (int)hl[w][(t - t0 - 1) * KK + cur];  // path[t-1]=hist_t[path[t]]
            }
        }
    }
}

extern "C" void kernel_launch(void* const* d_in, const int* in_sizes, int n_in,
                              void* d_out, int out_size, void* d_ws, size_t ws_size,
                              hipStream_t stream) {
    const int*   words  = (const int*)d_in[0];
    const int*   tags   = (const int*)d_in[1];
    const float* wf     = (const float*)d_in[2];
    const float* W      = (const float*)d_in[3];
    const float* bias   = (const float*)d_in[4];
    const float* startv = (const float*)d_in[5];
    const float* endv   = (const float*)d_in[6];
    const float* trans  = (const float*)d_in[7];

    // workspace layout (float units unless noted)
    float* em   = (float*)d_ws;                       // 512*64*10 = 327680
    float* Mlse = em + 327680;                        // 64*16*100 = 102400
    float* Mmax = Mlse + 102400;                      // 102400
    float* ubnd = Mmax + 102400;                      // 64*16*10 = 10240
    int*   lenA = (int*)(ubnd + 10240);               // 64
    int*   ltag = lenA + 64;                          // 64
    int*   Fmap = ltag + 64;                          // 64*16*10 = 10240
    uchar* hist = (uchar*)(Fmap + 10240);             // 64*16*320 bytes

    int*   paths     = (int*)d_out;                   // (T,B) int32 values
    float* loss_slot = ((float*)d_out) + TT * BB;     // scalar f32

    k_emissions<<<513, 256, 0, stream>>>(words, wf, W, bias, em, lenA, loss_slot);
    k_chunk<<<2048, 128, 0, stream>>>(em, trans, lenA, Mlse, Mmax);
    k_fold<<<128, 64, 0, stream>>>(tags, em, startv, endv, trans, lenA, Mlse, Mmax,
                                   ubnd, ltag, loss_slot);
    k_hist<<<1024, 64, 0, stream>>>(em, trans, lenA, ubnd, Fmap, hist);
    k_paths<<<64, 1024, 0, stream>>>(lenA, ltag, Fmap, hist, paths);
}

// Round 3
// 108.282 us; speedup vs baseline: 1.6262x; 1.1179x over previous
//
#include <hip/hip_runtime.h>
#include <hip/hip_bf16.h>

#define TT 512
#define BB 64
#define KK 10
#define DD 1024
#define CL 32   // chunk length (steps per chunk)
#define NC 16   // number of chunks

typedef unsigned char uchar;

__device__ __forceinline__ float max10(const float* r) {
    float m0 = fmaxf(r[0], r[1]), m1 = fmaxf(r[2], r[3]);
    float m2 = fmaxf(r[4], r[5]), m3 = fmaxf(r[6], r[7]);
    float m4 = fmaxf(r[8], r[9]);
    m0 = fmaxf(m0, m1); m2 = fmaxf(m2, m3); m0 = fmaxf(m0, m2);
    return fmaxf(m0, m4);
}

__device__ __forceinline__ float lse10(const float* r) {
    const float m = max10(r);
    float s0 = __expf(r[0] - m) + __expf(r[1] - m);
    float s1 = __expf(r[2] - m) + __expf(r[3] - m);
    float s2 = __expf(r[4] - m) + __expf(r[5] - m);
    float s3 = __expf(r[6] - m) + __expf(r[7] - m);
    float s4 = __expf(r[8] - m) + __expf(r[9] - m);
    return m + __logf(((s0 + s1) + (s2 + s3)) + s4);
}

// ---------------- Kernel A: emissions + lengths -----------------------------
// blocks 0..1023: 32 rows each (4 waves x 8 rows, 1 row per iter, prefetched).
// block 1024: lengths per batch + zero loss slot.
__global__ __launch_bounds__(256) void k_emissions(
    const int* __restrict__ words, const float* __restrict__ wf,
    const float* __restrict__ W, const float* __restrict__ bias,
    float* __restrict__ em, int* __restrict__ lenArr, float* loss_slot) {
    const int tid = threadIdx.x;
    if (blockIdx.x == 1024) {
        __shared__ int cnt[4][64];
        const int b = tid & 63, seg = tid >> 6;
        int c = 0;
        for (int t = seg; t < TT; t += 4) c += (words[t * BB + b] != 0) ? 1 : 0;
        cnt[seg][b] = c;
        __syncthreads();
        if (tid < 64) lenArr[tid] = cnt[0][tid] + cnt[1][tid] + cnt[2][tid] + cnt[3][tid];
        if (tid == 0) *loss_slot = 0.f;
        return;
    }
    __shared__ float Wt[KK][DD];  // 40 KB, W transposed, XOR-swizzled columns
    for (int idx = tid; idx < DD * KK; idx += 256) {
        const int d = idx / KK, k = idx - d * KK;
        Wt[k][d ^ (k << 2)] = W[idx];   // write banks spread (<=2-way)
    }
    __syncthreads();
    const int wave = tid >> 6, lane = tid & 63;
    float bk[KK];
    #pragma unroll
    for (int k = 0; k < KK; ++k) bk[k] = bias[k];

    const int row0 = blockIdx.x * 32 + wave * 8;
    // prefetch first float4 of first row
    float4 f = *reinterpret_cast<const float4*>(wf + (size_t)row0 * DD + lane * 4);

    for (int r = 0; r < 8; ++r) {
        const size_t base = (size_t)(row0 + r) * DD;
        float acc[KK];
        #pragma unroll
        for (int k = 0; k < KK; ++k) acc[k] = 0.f;
        #pragma unroll
        for (int it = 0; it < 4; ++it) {
            const float4 fc = f;
            if (r < 7 || it < 3) {   // prefetch next (next it, or next row's it0)
                const size_t nb = (it == 3) ? base + DD : base;
                const int nd0 = (it == 3) ? 0 : (it + 1) * 256;
                f = *reinterpret_cast<const float4*>(wf + nb + nd0 + lane * 4);
            }
            const int d0 = it * 256 + lane * 4;
            #pragma unroll
            for (int k = 0; k < KK; ++k) {
                const float4 w = *reinterpret_cast<const float4*>(&Wt[k][d0 ^ (k << 2)]);
                acc[k] += fc.x * w.x + fc.y * w.y + fc.z * w.z + fc.w * w.w;
            }
        }
        #pragma unroll
        for (int off = 32; off >= 1; off >>= 1)
            #pragma unroll
            for (int k = 0; k < KK; ++k) acc[k] += __shfl_xor(acc[k], off);
        #pragma unroll
        for (int k = 0; k < KK; ++k)
            if (lane == k) em[(size_t)(row0 + r) * KK + k] = acc[k] + bk[k];
    }
}

// ---------------- Kernel B: per-chunk 10x10 transfer matrices ---------------
// grid 2048: blockIdx = sem*1024 + b*16 + c; 128 threads, (i,j) = tid/10,tid%10.
// Chunk c covers steps s in [32c+1, min(32c+32, len-1)].
__global__ __launch_bounds__(128) void k_chunk(
    const float* __restrict__ em, const float* __restrict__ trans,
    const int* __restrict__ lenArr, float* __restrict__ Mlse, float* __restrict__ Mmax) {
    int id = blockIdx.x;
    const bool mx = id >= 1024; id &= 1023;
    const int b = id >> 4, c = id & 15;
    const int len = lenArr[b];
    const int s_lo = c * CL + 1;
    const int s_hi = min(c * CL + CL, len - 1);
    const int ns = s_hi - s_lo + 1;
    if (ns <= 0) return;  // identity chunk: consumers skip it

    __shared__ float Ms[KK][12];
    __shared__ float eml[CL][KK];
    const int tid = threadIdx.x;
    for (int idx = tid; idx < CL * KK; idx += 128) {
        const int sl = idx / KK, j = idx % KK;
        const int s = s_lo + sl;
        eml[sl][j] = (s <= TT - 1) ? em[((size_t)s * BB + b) * KK + j] : 0.f;
    }
    const int i = tid / KK, j = tid % KK;
    const bool act = tid < KK * KK;
    float trc[KK];
    if (act) {
        #pragma unroll
        for (int k = 0; k < KK; ++k) trc[k] = trans[k * KK + j];
    }
    __syncthreads();
    float cur = 0.f;
    if (act) { cur = trans[i * KK + j] + eml[0][j]; Ms[i][j] = cur; }
    __syncthreads();
    for (int sl = 1; sl < ns; ++sl) {
        float row[KK];
        if (act) {
            #pragma unroll
            for (int k = 0; k < KK; ++k) row[k] = Ms[i][k] + trc[k];
        }
        __syncthreads();
        if (act) {
            cur = (mx ? max10(row) : lse10(row)) + eml[sl][j];
            Ms[i][j] = cur;
        }
        __syncthreads();
    }
    if (act) {
        float* out = mx ? Mmax : Mlse;
        out[((size_t)b * NC + c) * 100 + i * KK + j] = cur;
    }
}

// ---------------- Kernel C: fold chunks per batch ---------------------------
// grid 128 x 64: blocks 0..63 = LSE (loss), 64..127 = max-plus (boundaries+last_tag)
__global__ __launch_bounds__(64) void k_fold(
    const int* __restrict__ tags, const float* __restrict__ em,
    const float* __restrict__ startv, const float* __restrict__ endv,
    const float* __restrict__ trans, const int* __restrict__ lenArr,
    const float* __restrict__ Mlse, const float* __restrict__ Mmax,
    float* __restrict__ ubnd, int* __restrict__ ltag, float* loss_slot) {
    const int b = blockIdx.x & 63;
    const bool mx = blockIdx.x >= 64;
    const int lane = threadIdx.x;
    const int len = lenArr[b];

    float v[KK];
    #pragma unroll
    for (int i = 0; i < KK; ++i) v[i] = startv[i] + em[(size_t)b * KK + i];

    const float* M = mx ? Mmax : Mlse;
    for (int c = 0; c < NC; ++c) {
        if (mx && lane < KK) ubnd[((size_t)b * NC + c) * KK + lane] = v[lane];
        const int s_lo = c * CL + 1;
        const int s_hi = min(c * CL + CL, len - 1);
        if (s_hi >= s_lo) {
            float nv = 0.f;
            if (lane < KK) {
                float r[KK];
                #pragma unroll
                for (int k = 0; k < KK; ++k)
                    r[k] = v[k] + M[((size_t)b * NC + c) * 100 + k * KK + lane];
                nv = mx ? max10(r) : lse10(r);
            }
            #pragma unroll
            for (int i = 0; i < KK; ++i) v[i] = __shfl(nv, i);
        }
    }

    if (mx) {
        // last_tag = argmax(v + end), first-index tie-break
        float best = v[0] + endv[0];
        int bi = 0;
        #pragma unroll
        for (int i = 1; i < KK; ++i) {
            const float x = v[i] + endv[i];
            if (x > best) { best = x; bi = i; }
        }
        if (lane == 0) ltag[b] = bi;
    } else {
        float r[KK];
        #pragma unroll
        for (int i = 0; i < KK; ++i) r[i] = v[i] + endv[i];
        const float denom = lse10(r);
        // numerator (gold path)
        float part = 0.f;
        for (int t = 1 + lane; t < len; t += 64) {
            const int tp = tags[(t - 1) * BB + b];
            const int tc = tags[t * BB + b];
            part += trans[tp * KK + tc] + em[((size_t)t * BB + b) * KK + tc];
        }
        #pragma unroll
        for (int off = 32; off >= 1; off >>= 1) part += __shfl_xor(part, off);
        const int t0 = tags[b];
        const int te = tags[(len - 1) * BB + b];
        const float numer = part + startv[t0] + em[(size_t)b * KK + t0] + endv[te];
        if (lane == 0) atomicAdd(loss_slot, denom - numer);
    }
}

// ---------------- Kernel D: per-chunk Viterbi re-run + backtrace map --------
// grid 1024: (b, c); 64 threads; lane j owns state j.
__global__ __launch_bounds__(64) void k_hist(
    const float* __restrict__ em, const float* __restrict__ trans,
    const int* __restrict__ lenArr, const float* __restrict__ ubnd,
    int* __restrict__ Fmap, uchar* __restrict__ hist) {
    const int b = blockIdx.x >> 4, c = blockIdx.x & 15;
    const int len = lenArr[b];
    const int s_lo = c * CL + 1;
    const int s_hi = min(c * CL + CL, len - 1);
    const int ns = s_hi - s_lo + 1;
    if (ns <= 0) return;  // identity chunk

    __shared__ float eml[CL][KK];
    __shared__ uchar hl[CL * KK];
    const int lane = threadIdx.x, j = lane;
    for (int idx = lane; idx < CL * KK; idx += 64) {
        const int sl = idx / KK, jj = idx % KK;
        const int s = s_lo + sl;
        eml[sl][jj] = (s <= TT - 1) ? em[((size_t)s * BB + b) * KK + jj] : 0.f;
    }
    float trc[KK];
    if (j < KK) {
        #pragma unroll
        for (int i = 0; i < KK; ++i) trc[i] = trans[i * KK + j];
    }
    float s[KK];
    #pragma unroll
    for (int i = 0; i < KK; ++i) s[i] = ubnd[((size_t)b * NC + c) * KK + i];
    __syncthreads();

    for (int sl = 0; sl < ns; ++sl) {
        float best = s[0] + trc[0];
        int bi = 0;
        #pragma unroll
        for (int i = 1; i < KK; ++i) {
            const float x = s[i] + trc[i];
            if (x > best) { best = x; bi = i; }
        }
        const float snew = best + eml[sl][j];
        if (j < KK) hl[sl * KK + j] = (uchar)bi;
        #pragma unroll
        for (int i = 0; i < KK; ++i) s[i] = __shfl(snew, i);
    }
    __syncthreads();
    // F_c(j): compose backpointers within the chunk (maps path[s_hi] -> path[32c])
    if (j < KK) {
        int cur = j;
        for (int sl = ns - 1; sl >= 0; --sl) cur = hl[sl * KK + cur];
        Fmap[((size_t)b * NC + c) * KK + j] = cur;
    }
    __syncthreads();
    const int* hli = (const int*)&hl[0];
    int* hg = (int*)(hist + ((size_t)b * NC + c) * (CL * KK));
    for (int idx = lane; idx < CL * KK / 4; idx += 64) hg[idx] = hli[idx];
}

// ---------------- Kernel E: boundary-tag fold + parallel path emit ----------
// grid 64 (per b) x 1024 threads (16 waves; wave w emits chunk w's path slice)
__global__ __launch_bounds__(1024) void k_paths(
    const int* __restrict__ lenArr, const int* __restrict__ ltag,
    const int* __restrict__ Fmap, const uchar* __restrict__ hist,
    int* __restrict__ paths) {
    const int b = blockIdx.x;
    const int len = lenArr[b];
    const int tid = threadIdx.x;
    __shared__ int Fl[NC][KK];
    __shared__ uchar hl[NC][CL * KK];
    __shared__ int vt[NC + 1];

    for (int idx = tid; idx < NC * KK; idx += 1024)
        Fl[idx / KK][idx % KK] = Fmap[(size_t)b * NC * KK + idx];
    const int* hg = (const int*)(hist + (size_t)b * NC * CL * KK);
    int* hls = (int*)&hl[0][0];
    for (int idx = tid; idx < NC * CL * KK / 4; idx += 1024) hls[idx] = hg[idx];
    __syncthreads();

    if (tid == 0) {
        int cur = ltag[b];
        vt[NC] = cur;
        for (int c = NC - 1; c >= 0; --c) {
            const int s_lo = c * CL + 1;
            const int s_hi = min(c * CL + CL, len - 1);
            if (s_hi >= s_lo) cur = Fl[c][cur];
            vt[c] = cur;
        }
    }
    __syncthreads();

    const int w = tid >> 6, lane = tid & 63;
    const int t0 = w * CL;
    if (lane < CL) {
        const int t = t0 + lane;
        if (t >= len) paths[t * BB + b] = 0;
    }
    if (lane == 0) {
        const int a = min(t0 + CL, len - 1);
        if (a >= t0) {
            int cur = vt[w + 1];  // = path[a]
            for (int t = a; t >= t0; --t) {
                if (t <= t0 + CL - 1) paths[t * BB + b] = cur;
                if (t > t0) cur = (int)hl[w][(t - t0 - 1) * KK + cur];  // path[t-1]=hist_t[path[t]]
            }
        }
    }
}

extern "C" void kernel_launch(void* const* d_in, const int* in_sizes, int n_in,
                              void* d_out, int out_size, void* d_ws, size_t ws_size,
                              hipStream_t stream) {
    const int*   words  = (const int*)d_in[0];
    const int*   tags   = (const int*)d_in[1];
    const float* wf     = (const float*)d_in[2];
    const float* W      = (const float*)d_in[3];
    const float* bias   = (const float*)d_in[4];
    const float* startv = (const float*)d_in[5];
    const float* endv   = (const float*)d_in[6];
    const float* trans  = (const float*)d_in[7];

    // workspace layout (float units unless noted)
    float* em   = (float*)d_ws;                       // 512*64*10 = 327680
    float* Mlse = em + 327680;                        // 64*16*100 = 102400
    float* Mmax = Mlse + 102400;                      // 102400
    float* ubnd = Mmax + 102400;                      // 64*16*10 = 10240
    int*   lenA = (int*)(ubnd + 10240);               // 64
    int*   ltag = lenA + 64;                          // 64
    int*   Fmap = ltag + 64;                          // 64*16*10 = 10240
    uchar* hist = (uchar*)(Fmap + 10240);             // 64*16*320 bytes

    int*   paths     = (int*)d_out;                   // (T,B) int32 values
    float* loss_slot = ((float*)d_out) + TT * BB;     // scalar f32

    k_emissions<<<1025, 256, 0, stream>>>(words, wf, W, bias, em, lenA, loss_slot);
    k_chunk<<<2048, 128, 0, stream>>>(em, trans, lenA, Mlse, Mmax);
    k_fold<<<128, 64, 0, stream>>>(tags, em, startv, endv, trans, lenA, Mlse, Mmax,
                                   ubnd, ltag, loss_slot);
    k_hist<<<1024, 64, 0, stream>>>(em, trans, lenA, ubnd, Fmap, hist);
    k_paths<<<64, 1024, 0, stream>>>(lenA, ltag, Fmap, hist, paths);
}

// Round 4
// 101.571 us; speedup vs baseline: 1.7336x; 1.0661x over previous
//
#include <hip/hip_runtime.h>
#include <hip/hip_bf16.h>

#define TT 512
#define BB 64
#define KK 10
#define DD 1024
#define CL 32   // chunk length (steps per chunk)
#define NC 16   // number of chunks

typedef unsigned char uchar;

__device__ __forceinline__ float max10(const float* r) {
    float m0 = fmaxf(r[0], r[1]), m1 = fmaxf(r[2], r[3]);
    float m2 = fmaxf(r[4], r[5]), m3 = fmaxf(r[6], r[7]);
    float m4 = fmaxf(r[8], r[9]);
    m0 = fmaxf(m0, m1); m2 = fmaxf(m2, m3); m0 = fmaxf(m0, m2);
    return fmaxf(m0, m4);
}

__device__ __forceinline__ float lse10(const float* r) {
    const float m = max10(r);
    float s0 = __expf(r[0] - m) + __expf(r[1] - m);
    float s1 = __expf(r[2] - m) + __expf(r[3] - m);
    float s2 = __expf(r[4] - m) + __expf(r[5] - m);
    float s3 = __expf(r[6] - m) + __expf(r[7] - m);
    float s4 = __expf(r[8] - m) + __expf(r[9] - m);
    return m + __logf(((s0 + s1) + (s2 + s3)) + s4);
}

// ---------------- Kernel A: emissions + lengths -----------------------------
// blocks 0..511: 64 rows each (8 waves x 8 rows). Row-level double buffer:
// all 4 float4 loads of row r+1 are in flight while row r computes (4 KB MLP).
// block 512: lengths per batch + zero loss slot.
__global__ __launch_bounds__(512) void k_emissions(
    const int* __restrict__ words, const float* __restrict__ wf,
    const float* __restrict__ W, const float* __restrict__ bias,
    float* __restrict__ em, int* __restrict__ lenArr, float* loss_slot) {
    const int tid = threadIdx.x;
    if (blockIdx.x == 512) {
        __shared__ int cnt[8][64];
        const int b = tid & 63, seg = tid >> 6;
        int c = 0;
        for (int t = seg; t < TT; t += 8) c += (words[t * BB + b] != 0) ? 1 : 0;
        cnt[seg][b] = c;
        __syncthreads();
        if (tid < 64) {
            int s = 0;
            #pragma unroll
            for (int g = 0; g < 8; ++g) s += cnt[g][tid];
            lenArr[tid] = s;
        }
        if (tid == 0) *loss_slot = 0.f;
        return;
    }
    __shared__ float Wt[KK][DD];  // 40 KB, W transposed, XOR-swizzled columns
    for (int idx = tid; idx < DD * KK; idx += 512) {
        const int d = idx / KK, k = idx - d * KK;
        Wt[k][d ^ (k << 2)] = W[idx];   // write banks spread (<=2-way)
    }
    __syncthreads();
    const int wave = tid >> 6, lane = tid & 63;
    float bk[KK];
    #pragma unroll
    for (int k = 0; k < KK; ++k) bk[k] = bias[k];

    const int row0 = blockIdx.x * 64 + wave * 8;
    const float* p = wf + (size_t)row0 * DD + lane * 4;

    float4 cur0 = *reinterpret_cast<const float4*>(p + 0 * 256);
    float4 cur1 = *reinterpret_cast<const float4*>(p + 1 * 256);
    float4 cur2 = *reinterpret_cast<const float4*>(p + 2 * 256);
    float4 cur3 = *reinterpret_cast<const float4*>(p + 3 * 256);

    #pragma unroll 1
    for (int r = 0; r < 8; ++r) {
        // issue next row's 4 loads first (stay in flight under this row's math)
        float4 nxt0, nxt1, nxt2, nxt3;
        if (r < 7) {
            const float* q = p + (size_t)(r + 1) * DD;
            nxt0 = *reinterpret_cast<const float4*>(q + 0 * 256);
            nxt1 = *reinterpret_cast<const float4*>(q + 1 * 256);
            nxt2 = *reinterpret_cast<const float4*>(q + 2 * 256);
            nxt3 = *reinterpret_cast<const float4*>(q + 3 * 256);
        }
        float acc[KK];
        #pragma unroll
        for (int k = 0; k < KK; ++k) acc[k] = 0.f;
        const float4 fr[4] = {cur0, cur1, cur2, cur3};
        #pragma unroll
        for (int it = 0; it < 4; ++it) {
            const float4 fc = fr[it];
            const int d0 = it * 256 + lane * 4;
            #pragma unroll
            for (int k = 0; k < KK; ++k) {
                const float4 w = *reinterpret_cast<const float4*>(&Wt[k][d0 ^ (k << 2)]);
                acc[k] += fc.x * w.x + fc.y * w.y + fc.z * w.z + fc.w * w.w;
            }
        }
        #pragma unroll
        for (int off = 32; off >= 1; off >>= 1)
            #pragma unroll
            for (int k = 0; k < KK; ++k) acc[k] += __shfl_xor(acc[k], off);
        #pragma unroll
        for (int k = 0; k < KK; ++k)
            if (lane == k) em[(size_t)(row0 + r) * KK + k] = acc[k] + bk[k];
        cur0 = nxt0; cur1 = nxt1; cur2 = nxt2; cur3 = nxt3;
    }
}

// ---------------- Kernel B: per-chunk 10x10 transfer matrices ---------------
// grid 2048: blockIdx = sem*1024 + b*16 + c; 128 threads, (i,j) = tid/10,tid%10.
// Chunk c covers steps s in [32c+1, min(32c+32, len-1)].
__global__ __launch_bounds__(128) void k_chunk(
    const float* __restrict__ em, const float* __restrict__ trans,
    const int* __restrict__ lenArr, float* __restrict__ Mlse, float* __restrict__ Mmax) {
    int id = blockIdx.x;
    const bool mx = id >= 1024; id &= 1023;
    const int b = id >> 4, c = id & 15;
    const int len = lenArr[b];
    const int s_lo = c * CL + 1;
    const int s_hi = min(c * CL + CL, len - 1);
    const int ns = s_hi - s_lo + 1;
    if (ns <= 0) return;  // identity chunk: consumers skip it

    __shared__ float Ms[KK][12];
    __shared__ float eml[CL][KK];
    const int tid = threadIdx.x;
    for (int idx = tid; idx < CL * KK; idx += 128) {
        const int sl = idx / KK, j = idx % KK;
        const int s = s_lo + sl;
        eml[sl][j] = (s <= TT - 1) ? em[((size_t)s * BB + b) * KK + j] : 0.f;
    }
    const int i = tid / KK, j = tid % KK;
    const bool act = tid < KK * KK;
    float trc[KK];
    if (act) {
        #pragma unroll
        for (int k = 0; k < KK; ++k) trc[k] = trans[k * KK + j];
    }
    __syncthreads();
    float cur = 0.f;
    if (act) { cur = trans[i * KK + j] + eml[0][j]; Ms[i][j] = cur; }
    __syncthreads();
    for (int sl = 1; sl < ns; ++sl) {
        float row[KK];
        if (act) {
            #pragma unroll
            for (int k = 0; k < KK; ++k) row[k] = Ms[i][k] + trc[k];
        }
        __syncthreads();
        if (act) {
            cur = (mx ? max10(row) : lse10(row)) + eml[sl][j];
            Ms[i][j] = cur;
        }
        __syncthreads();
    }
    if (act) {
        float* out = mx ? Mmax : Mlse;
        out[((size_t)b * NC + c) * 100 + i * KK + j] = cur;
    }
}

// ---------------- Kernel C: fold chunks per batch ---------------------------
// grid 128 x 64: blocks 0..63 = LSE (loss), 64..127 = max-plus (boundaries+last_tag)
__global__ __launch_bounds__(64) void k_fold(
    const int* __restrict__ tags, const float* __restrict__ em,
    const float* __restrict__ startv, const float* __restrict__ endv,
    const float* __restrict__ trans, const int* __restrict__ lenArr,
    const float* __restrict__ Mlse, const float* __restrict__ Mmax,
    float* __restrict__ ubnd, int* __restrict__ ltag, float* loss_slot) {
    const int b = blockIdx.x & 63;
    const bool mx = blockIdx.x >= 64;
    const int lane = threadIdx.x;
    const int len = lenArr[b];

    float v[KK];
    #pragma unroll
    for (int i = 0; i < KK; ++i) v[i] = startv[i] + em[(size_t)b * KK + i];

    const float* M = mx ? Mmax : Mlse;
    for (int c = 0; c < NC; ++c) {
        if (mx && lane < KK) ubnd[((size_t)b * NC + c) * KK + lane] = v[lane];
        const int s_lo = c * CL + 1;
        const int s_hi = min(c * CL + CL, len - 1);
        if (s_hi >= s_lo) {
            float nv = 0.f;
            if (lane < KK) {
                float r[KK];
                #pragma unroll
                for (int k = 0; k < KK; ++k)
                    r[k] = v[k] + M[((size_t)b * NC + c) * 100 + k * KK + lane];
                nv = mx ? max10(r) : lse10(r);
            }
            #pragma unroll
            for (int i = 0; i < KK; ++i) v[i] = __shfl(nv, i);
        }
    }

    if (mx) {
        // last_tag = argmax(v + end), first-index tie-break
        float best = v[0] + endv[0];
        int bi = 0;
        #pragma unroll
        for (int i = 1; i < KK; ++i) {
            const float x = v[i] + endv[i];
            if (x > best) { best = x; bi = i; }
        }
        if (lane == 0) ltag[b] = bi;
    } else {
        float r[KK];
        #pragma unroll
        for (int i = 0; i < KK; ++i) r[i] = v[i] + endv[i];
        const float denom = lse10(r);
        // numerator (gold path)
        float part = 0.f;
        for (int t = 1 + lane; t < len; t += 64) {
            const int tp = tags[(t - 1) * BB + b];
            const int tc = tags[t * BB + b];
            part += trans[tp * KK + tc] + em[((size_t)t * BB + b) * KK + tc];
        }
        #pragma unroll
        for (int off = 32; off >= 1; off >>= 1) part += __shfl_xor(part, off);
        const int t0 = tags[b];
        const int te = tags[(len - 1) * BB + b];
        const float numer = part + startv[t0] + em[(size_t)b * KK + t0] + endv[te];
        if (lane == 0) atomicAdd(loss_slot, denom - numer);
    }
}

// ---------------- Kernel D: per-chunk Viterbi re-run + backtrace map --------
// grid 1024: (b, c); 64 threads; lane j owns state j.
__global__ __launch_bounds__(64) void k_hist(
    const float* __restrict__ em, const float* __restrict__ trans,
    const int* __restrict__ lenArr, const float* __restrict__ ubnd,
    int* __restrict__ Fmap, uchar* __restrict__ hist) {
    const int b = blockIdx.x >> 4, c = blockIdx.x & 15;
    const int len = lenArr[b];
    const int s_lo = c * CL + 1;
    const int s_hi = min(c * CL + CL, len - 1);
    const int ns = s_hi - s_lo + 1;
    if (ns <= 0) return;  // identity chunk

    __shared__ float eml[CL][KK];
    __shared__ uchar hl[CL * KK];
    const int lane = threadIdx.x, j = lane;
    for (int idx = lane; idx < CL * KK; idx += 64) {
        const int sl = idx / KK, jj = idx % KK;
        const int s = s_lo + sl;
        eml[sl][jj] = (s <= TT - 1) ? em[((size_t)s * BB + b) * KK + jj] : 0.f;
    }
    float trc[KK];
    if (j < KK) {
        #pragma unroll
        for (int i = 0; i < KK; ++i) trc[i] = trans[i * KK + j];
    }
    float s[KK];
    #pragma unroll
    for (int i = 0; i < KK; ++i) s[i] = ubnd[((size_t)b * NC + c) * KK + i];
    __syncthreads();

    for (int sl = 0; sl < ns; ++sl) {
        float best = s[0] + trc[0];
        int bi = 0;
        #pragma unroll
        for (int i = 1; i < KK; ++i) {
            const float x = s[i] + trc[i];
            if (x > best) { best = x; bi = i; }
        }
        const float snew = best + eml[sl][j];
        if (j < KK) hl[sl * KK + j] = (uchar)bi;
        #pragma unroll
        for (int i = 0; i < KK; ++i) s[i] = __shfl(snew, i);
    }
    __syncthreads();
    // F_c(j): compose backpointers within the chunk (maps path[s_hi] -> path[32c])
    if (j < KK) {
        int cur = j;
        for (int sl = ns - 1; sl >= 0; --sl) cur = hl[sl * KK + cur];
        Fmap[((size_t)b * NC + c) * KK + j] = cur;
    }
    __syncthreads();
    const int* hli = (const int*)&hl[0];
    int* hg = (int*)(hist + ((size_t)b * NC + c) * (CL * KK));
    for (int idx = lane; idx < CL * KK / 4; idx += 64) hg[idx] = hli[idx];
}

// ---------------- Kernel E: boundary-tag fold + parallel path emit ----------
// grid 64 (per b) x 1024 threads (16 waves; wave w emits chunk w's path slice)
__global__ __launch_bounds__(1024) void k_paths(
    const int* __restrict__ lenArr, const int* __restrict__ ltag,
    const int* __restrict__ Fmap, const uchar* __restrict__ hist,
    int* __restrict__ paths) {
    const int b = blockIdx.x;
    const int len = lenArr[b];
    const int tid = threadIdx.x;
    __shared__ int Fl[NC][KK];
    __shared__ uchar hl[NC][CL * KK];
    __shared__ int vt[NC + 1];

    for (int idx = tid; idx < NC * KK; idx += 1024)
        Fl[idx / KK][idx % KK] = Fmap[(size_t)b * NC * KK + idx];
    const int* hg = (const int*)(hist + (size_t)b * NC * CL * KK);
    int* hls = (int*)&hl[0][0];
    for (int idx = tid; idx < NC * CL * KK / 4; idx += 1024) hls[idx] = hg[idx];
    __syncthreads();

    if (tid == 0) {
        int cur = ltag[b];
        vt[NC] = cur;
        for (int c = NC - 1; c >= 0; --c) {
            const int s_lo = c * CL + 1;
            const int s_hi = min(c * CL + CL, len - 1);
            if (s_hi >= s_lo) cur = Fl[c][cur];
            vt[c] = cur;
        }
    }
    __syncthreads();

    const int w = tid >> 6, lane = tid & 63;
    const int t0 = w * CL;
    if (lane < CL) {
        const int t = t0 + lane;
        if (t >= len) paths[t * BB + b] = 0;
    }
    if (lane == 0) {
        const int a = min(t0 + CL, len - 1);
        if (a >= t0) {
            int cur = vt[w + 1];  // = path[a]
            for (int t = a; t >= t0; --t) {
                if (t <= t0 + CL - 1) paths[t * BB + b] = cur;
                if (t > t0) cur = (int)hl[w][(t - t0 - 1) * KK + cur];  // path[t-1]=hist_t[path[t]]
            }
        }
    }
}

extern "C" void kernel_launch(void* const* d_in, const int* in_sizes, int n_in,
                              void* d_out, int out_size, void* d_ws, size_t ws_size,
                              hipStream_t stream) {
    const int*   words  = (const int*)d_in[0];
    const int*   tags   = (const int*)d_in[1];
    const float* wf     = (const float*)d_in[2];
    const float* W      = (const float*)d_in[3];
    const float* bias   = (const float*)d_in[4];
    const float* startv = (const float*)d_in[5];
    const float* endv   = (const float*)d_in[6];
    const float* trans  = (const float*)d_in[7];

    // workspace layout (float units unless noted)
    float* em   = (float*)d_ws;                       // 512*64*10 = 327680
    float* Mlse = em + 327680;                        // 64*16*100 = 102400
    float* Mmax = Mlse + 102400;                      // 102400
    float* ubnd = Mmax + 102400;                      // 64*16*10 = 10240
    int*   lenA = (int*)(ubnd + 10240);               // 64
    int*   ltag = lenA + 64;                          // 64
    int*   Fmap = ltag + 64;                          // 64*16*10 = 10240
    uchar* hist = (uchar*)(Fmap + 10240);             // 64*16*320 bytes

    int*   paths     = (int*)d_out;                   // (T,B) int32 values
    float* loss_slot = ((float*)d_out) + TT * BB;     // scalar f32

    k_emissions<<<513, 512, 0, stream>>>(words, wf, W, bias, em, lenA, loss_slot);
    k_chunk<<<2048, 128, 0, stream>>>(em, trans, lenA, Mlse, Mmax);
    k_fold<<<128, 64, 0, stream>>>(tags, em, startv, endv, trans, lenA, Mlse, Mmax,
                                   ubnd, ltag, loss_slot);
    k_hist<<<1024, 64, 0, stream>>>(em, trans, lenA, ubnd, Fmap, hist);
    k_paths<<<64, 1024, 0, stream>>>(lenA, ltag, Fmap, hist, paths);
}

// Round 5
// 81.554 us; speedup vs baseline: 2.1591x; 1.2454x over previous
//
#include <hip/hip_runtime.h>
#include <hip/hip_bf16.h>

#define TT 512
#define BB 64
#define KK 10
#define DD 1024
#define CL 32   // chunk length (steps per chunk)
#define NC 16   // number of chunks

typedef unsigned char uchar;
typedef short bf16x8 __attribute__((ext_vector_type(8)));
typedef float f32x4 __attribute__((ext_vector_type(4)));

__device__ __forceinline__ unsigned f2bf(float f) {  // RNE f32 -> bf16 bits
    unsigned u = __float_as_uint(f);
    return (u + 0x7FFFu + ((u >> 16) & 1u)) >> 16;
}

__device__ __forceinline__ float max10(const float* r) {
    float m0 = fmaxf(r[0], r[1]), m1 = fmaxf(r[2], r[3]);
    float m2 = fmaxf(r[4], r[5]), m3 = fmaxf(r[6], r[7]);
    float m4 = fmaxf(r[8], r[9]);
    m0 = fmaxf(m0, m1); m2 = fmaxf(m2, m3); m0 = fmaxf(m0, m2);
    return fmaxf(m0, m4);
}

__device__ __forceinline__ float lse10(const float* r) {
    const float m = max10(r);
    float s0 = __expf(r[0] - m) + __expf(r[1] - m);
    float s1 = __expf(r[2] - m) + __expf(r[3] - m);
    float s2 = __expf(r[4] - m) + __expf(r[5] - m);
    float s3 = __expf(r[6] - m) + __expf(r[7] - m);
    float s4 = __expf(r[8] - m) + __expf(r[9] - m);
    return m + __logf(((s0 + s1) + (s2 + s3)) + s4);
}

// ---------------- Kernel A: emissions via MFMA + lengths --------------------
// blocks 0..255: 128 rows each (8 waves x one 16x16 MFMA tile, K=1024).
// block 256: lengths per batch + zero loss slot.
__global__ __launch_bounds__(512) void k_emissions(
    const int* __restrict__ words, const float* __restrict__ wf,
    const float* __restrict__ W, const float* __restrict__ bias,
    float* __restrict__ em, int* __restrict__ lenArr, float* loss_slot) {
    const int tid = threadIdx.x;
    if (blockIdx.x == 256) {
        __shared__ int cnt[8][64];
        const int b = tid & 63, seg = tid >> 6;
        int c = 0;
        for (int t = seg; t < TT; t += 8) c += (words[t * BB + b] != 0) ? 1 : 0;
        cnt[seg][b] = c;
        __syncthreads();
        if (tid < 64) {
            int s = 0;
            #pragma unroll
            for (int g = 0; g < 8; ++g) s += cnt[g][tid];
            lenArr[tid] = s;
        }
        if (tid == 0) *loss_slot = 0.f;
        return;
    }

    // B-fragment table: Bfrag[ks][lane] = 8 bf16 of W[ks*32 + (lane>>4)*8 + j][lane&15]
    __shared__ uint4 Bfrag[32][64];  // 32 KB
    for (int idx = tid; idx < 32 * 64; idx += 512) {
        const int ks = idx >> 6, l = idx & 63;
        const int col = l & 15, kg = l >> 4;
        unsigned u[4];
        #pragma unroll
        for (int p = 0; p < 4; ++p) {
            unsigned lo = 0, hi = 0;
            if (col < KK) {
                const int k0 = ks * 32 + kg * 8 + p * 2;
                lo = f2bf(W[(size_t)k0 * KK + col]);
                hi = f2bf(W[(size_t)(k0 + 1) * KK + col]);
            }
            u[p] = lo | (hi << 16);
        }
        Bfrag[ks][l] = make_uint4(u[0], u[1], u[2], u[3]);
    }
    __syncthreads();

    const int wave = tid >> 6, lane = tid & 63;
    const int arow = lane & 15;      // A row within tile (== C col)
    const int kg   = lane >> 4;      // k-group (and C row-group)
    const int row0 = blockIdx.x * 128 + wave * 16;
    const float* ap = wf + (size_t)(row0 + arow) * DD + kg * 8;

    const float bk = bias[arow < KK ? arow : 0];

    f32x4 acc = {0.f, 0.f, 0.f, 0.f};
    float4 fa[4], fb[4];
    #pragma unroll
    for (int p = 0; p < 4; ++p) {
        fa[p] = *reinterpret_cast<const float4*>(ap + p * 32);
        fb[p] = *reinterpret_cast<const float4*>(ap + p * 32 + 4);
    }
    #pragma unroll
    for (int ks = 0; ks < 32; ++ks) {
        const int s = ks & 3;
        bf16x8 afr;
        afr[0] = (short)f2bf(fa[s].x); afr[1] = (short)f2bf(fa[s].y);
        afr[2] = (short)f2bf(fa[s].z); afr[3] = (short)f2bf(fa[s].w);
        afr[4] = (short)f2bf(fb[s].x); afr[5] = (short)f2bf(fb[s].y);
        afr[6] = (short)f2bf(fb[s].z); afr[7] = (short)f2bf(fb[s].w);
        union { uint4 u; bf16x8 v; } bu;
        bu.u = Bfrag[ks][lane];
        if (ks < 28) {  // prefetch ks+4 (4 KB in flight per wave)
            fa[s] = *reinterpret_cast<const float4*>(ap + (ks + 4) * 32);
            fb[s] = *reinterpret_cast<const float4*>(ap + (ks + 4) * 32 + 4);
        }
        acc = __builtin_amdgcn_mfma_f32_16x16x32_bf16(afr, bu.v, acc, 0, 0, 0);
    }
    // C layout: col = lane&15, row = (lane>>4)*4 + reg  [m89]
    if (arow < KK) {
        #pragma unroll
        for (int r = 0; r < 4; ++r)
            em[(size_t)(row0 + kg * 4 + r) * KK + arow] = acc[r] + bk;
    }
}

// ---------------- Kernel B: per-chunk 10x10 transfer matrices ---------------
// grid 2048: blockIdx = sem*1024 + b*16 + c; 128 threads, (i,j) = tid/10,tid%10.
// Chunk c covers steps s in [32c+1, min(32c+32, len-1)].
__global__ __launch_bounds__(128) void k_chunk(
    const float* __restrict__ em, const float* __restrict__ trans,
    const int* __restrict__ lenArr, float* __restrict__ Mlse, float* __restrict__ Mmax) {
    int id = blockIdx.x;
    const bool mx = id >= 1024; id &= 1023;
    const int b = id >> 4, c = id & 15;
    const int len = lenArr[b];
    const int s_lo = c * CL + 1;
    const int s_hi = min(c * CL + CL, len - 1);
    const int ns = s_hi - s_lo + 1;
    if (ns <= 0) return;  // identity chunk: consumers skip it

    __shared__ float Ms[KK][12];
    __shared__ float eml[CL][KK];
    const int tid = threadIdx.x;
    for (int idx = tid; idx < CL * KK; idx += 128) {
        const int sl = idx / KK, j = idx % KK;
        const int s = s_lo + sl;
        eml[sl][j] = (s <= TT - 1) ? em[((size_t)s * BB + b) * KK + j] : 0.f;
    }
    const int i = tid / KK, j = tid % KK;
    const bool act = tid < KK * KK;
    float trc[KK];
    if (act) {
        #pragma unroll
        for (int k = 0; k < KK; ++k) trc[k] = trans[k * KK + j];
    }
    __syncthreads();
    float cur = 0.f;
    if (act) { cur = trans[i * KK + j] + eml[0][j]; Ms[i][j] = cur; }
    __syncthreads();
    for (int sl = 1; sl < ns; ++sl) {
        float row[KK];
        if (act) {
            #pragma unroll
            for (int k = 0; k < KK; ++k) row[k] = Ms[i][k] + trc[k];
        }
        __syncthreads();
        if (act) {
            cur = (mx ? max10(row) : lse10(row)) + eml[sl][j];
            Ms[i][j] = cur;
        }
        __syncthreads();
    }
    if (act) {
        float* out = mx ? Mmax : Mlse;
        out[((size_t)b * NC + c) * 100 + i * KK + j] = cur;
    }
}

// ---------------- Kernel C: fold chunks per batch ---------------------------
// grid 128 x 64: blocks 0..63 = LSE (loss), 64..127 = max-plus (boundaries+last_tag)
__global__ __launch_bounds__(64) void k_fold(
    const int* __restrict__ tags, const float* __restrict__ em,
    const float* __restrict__ startv, const float* __restrict__ endv,
    const float* __restrict__ trans, const int* __restrict__ lenArr,
    const float* __restrict__ Mlse, const float* __restrict__ Mmax,
    float* __restrict__ ubnd, int* __restrict__ ltag, float* loss_slot) {
    const int b = blockIdx.x & 63;
    const bool mx = blockIdx.x >= 64;
    const int lane = threadIdx.x;
    const int len = lenArr[b];

    float v[KK];
    #pragma unroll
    for (int i = 0; i < KK; ++i) v[i] = startv[i] + em[(size_t)b * KK + i];

    const float* M = mx ? Mmax : Mlse;
    for (int c = 0; c < NC; ++c) {
        if (mx && lane < KK) ubnd[((size_t)b * NC + c) * KK + lane] = v[lane];
        const int s_lo = c * CL + 1;
        const int s_hi = min(c * CL + CL, len - 1);
        if (s_hi >= s_lo) {
            float nv = 0.f;
            if (lane < KK) {
                float r[KK];
                #pragma unroll
                for (int k = 0; k < KK; ++k)
                    r[k] = v[k] + M[((size_t)b * NC + c) * 100 + k * KK + lane];
                nv = mx ? max10(r) : lse10(r);
            }
            #pragma unroll
            for (int i = 0; i < KK; ++i) v[i] = __shfl(nv, i);
        }
    }

    if (mx) {
        // last_tag = argmax(v + end), first-index tie-break
        float best = v[0] + endv[0];
        int bi = 0;
        #pragma unroll
        for (int i = 1; i < KK; ++i) {
            const float x = v[i] + endv[i];
            if (x > best) { best = x; bi = i; }
        }
        if (lane == 0) ltag[b] = bi;
    } else {
        float r[KK];
        #pragma unroll
        for (int i = 0; i < KK; ++i) r[i] = v[i] + endv[i];
        const float denom = lse10(r);
        // numerator (gold path)
        float part = 0.f;
        for (int t = 1 + lane; t < len; t += 64) {
            const int tp = tags[(t - 1) * BB + b];
            const int tc = tags[t * BB + b];
            part += trans[tp * KK + tc] + em[((size_t)t * BB + b) * KK + tc];
        }
        #pragma unroll
        for (int off = 32; off >= 1; off >>= 1) part += __shfl_xor(part, off);
        const int t0 = tags[b];
        const int te = tags[(len - 1) * BB + b];
        const float numer = part + startv[t0] + em[(size_t)b * KK + t0] + endv[te];
        if (lane == 0) atomicAdd(loss_slot, denom - numer);
    }
}

// ---------------- Kernel D: per-chunk Viterbi re-run + backtrace map --------
// grid 1024: (b, c); 64 threads; lane j owns state j.
__global__ __launch_bounds__(64) void k_hist(
    const float* __restrict__ em, const float* __restrict__ trans,
    const int* __restrict__ lenArr, const float* __restrict__ ubnd,
    int* __restrict__ Fmap, uchar* __restrict__ hist) {
    const int b = blockIdx.x >> 4, c = blockIdx.x & 15;
    const int len = lenArr[b];
    const int s_lo = c * CL + 1;
    const int s_hi = min(c * CL + CL, len - 1);
    const int ns = s_hi - s_lo + 1;
    if (ns <= 0) return;  // identity chunk

    __shared__ float eml[CL][KK];
    __shared__ uchar hl[CL * KK];
    const int lane = threadIdx.x, j = lane;
    for (int idx = lane; idx < CL * KK; idx += 64) {
        const int sl = idx / KK, jj = idx % KK;
        const int s = s_lo + sl;
        eml[sl][jj] = (s <= TT - 1) ? em[((size_t)s * BB + b) * KK + jj] : 0.f;
    }
    float trc[KK];
    if (j < KK) {
        #pragma unroll
        for (int i = 0; i < KK; ++i) trc[i] = trans[i * KK + j];
    }
    float s[KK];
    #pragma unroll
    for (int i = 0; i < KK; ++i) s[i] = ubnd[((size_t)b * NC + c) * KK + i];
    __syncthreads();

    for (int sl = 0; sl < ns; ++sl) {
        float best = s[0] + trc[0];
        int bi = 0;
        #pragma unroll
        for (int i = 1; i < KK; ++i) {
            const float x = s[i] + trc[i];
            if (x > best) { best = x; bi = i; }
        }
        const float snew = best + eml[sl][j];
        if (j < KK) hl[sl * KK + j] = (uchar)bi;
        #pragma unroll
        for (int i = 0; i < KK; ++i) s[i] = __shfl(snew, i);
    }
    __syncthreads();
    // F_c(j): compose backpointers within the chunk (maps path[s_hi] -> path[32c])
    if (j < KK) {
        int cur = j;
        for (int sl = ns - 1; sl >= 0; --sl) cur = hl[sl * KK + cur];
        Fmap[((size_t)b * NC + c) * KK + j] = cur;
    }
    __syncthreads();
    const int* hli = (const int*)&hl[0];
    int* hg = (int*)(hist + ((size_t)b * NC + c) * (CL * KK));
    for (int idx = lane; idx < CL * KK / 4; idx += 64) hg[idx] = hli[idx];
}

// ---------------- Kernel E: boundary-tag fold + parallel path emit ----------
// grid 64 (per b) x 1024 threads (16 waves; wave w emits chunk w's path slice)
__global__ __launch_bounds__(1024) void k_paths(
    const int* __restrict__ lenArr, const int* __restrict__ ltag,
    const int* __restrict__ Fmap, const uchar* __restrict__ hist,
    int* __restrict__ paths) {
    const int b = blockIdx.x;
    const int len = lenArr[b];
    const int tid = threadIdx.x;
    __shared__ int Fl[NC][KK];
    __shared__ uchar hl[NC][CL * KK];
    __shared__ int vt[NC + 1];

    for (int idx = tid; idx < NC * KK; idx += 1024)
        Fl[idx / KK][idx % KK] = Fmap[(size_t)b * NC * KK + idx];
    const int* hg = (const int*)(hist + (size_t)b * NC * CL * KK);
    int* hls = (int*)&hl[0][0];
    for (int idx = tid; idx < NC * CL * KK / 4; idx += 1024) hls[idx] = hg[idx];
    __syncthreads();

    if (tid == 0) {
        int cur = ltag[b];
        vt[NC] = cur;
        for (int c = NC - 1; c >= 0; --c) {
            const int s_lo = c * CL + 1;
            const int s_hi = min(c * CL + CL, len - 1);
            if (s_hi >= s_lo) cur = Fl[c][cur];
            vt[c] = cur;
        }
    }
    __syncthreads();

    const int w = tid >> 6, lane = tid & 63;
    const int t0 = w * CL;
    if (lane < CL) {
        const int t = t0 + lane;
        if (t >= len) paths[t * BB + b] = 0;
    }
    if (lane == 0) {
        const int a = min(t0 + CL, len - 1);
        if (a >= t0) {
            int cur = vt[w + 1];  // = path[a]
            for (int t = a; t >= t0; --t) {
                if (t <= t0 + CL - 1) paths[t * BB + b] = cur;
                if (t > t0) cur = (int)hl[w][(t - t0 - 1) * KK + cur];  // path[t-1]=hist_t[path[t]]
            }
        }
    }
}

extern "C" void kernel_launch(void* const* d_in, const int* in_sizes, int n_in,
                              void* d_out, int out_size, void* d_ws, size_t ws_size,
                              hipStream_t stream) {
    const int*   words  = (const int*)d_in[0];
    const int*   tags   = (const int*)d_in[1];
    const float* wf     = (const float*)d_in[2];
    const float* W      = (const float*)d_in[3];
    const float* bias   = (const float*)d_in[4];
    const float* startv = (const float*)d_in[5];
    const float* endv   = (const float*)d_in[6];
    const float* trans  = (const float*)d_in[7];

    // workspace layout (float units unless noted)
    float* em   = (float*)d_ws;                       // 512*64*10 = 327680
    float* Mlse = em + 327680;                        // 64*16*100 = 102400
    float* Mmax = Mlse + 102400;                      // 102400
    float* ubnd = Mmax + 102400;                      // 64*16*10 = 10240
    int*   lenA = (int*)(ubnd + 10240);               // 64
    int*   ltag = lenA + 64;                          // 64
    int*   Fmap = ltag + 64;                          // 64*16*10 = 10240
    uchar* hist = (uchar*)(Fmap + 10240);             // 64*16*320 bytes

    int*   paths     = (int*)d_out;                   // (T,B) int32 values
    float* loss_slot = ((float*)d_out) + TT * BB;     // scalar f32

    k_emissions<<<257, 512, 0, stream>>>(words, wf, W, bias, em, lenA, loss_slot);
    k_chunk<<<2048, 128, 0, stream>>>(em, trans, lenA, Mlse, Mmax);
    k_fold<<<128, 64, 0, stream>>>(tags, em, startv, endv, trans, lenA, Mlse, Mmax,
                                   ubnd, ltag, loss_slot);
    k_hist<<<1024, 64, 0, stream>>>(em, trans, lenA, ubnd, Fmap, hist);
    k_paths<<<64, 1024, 0, stream>>>(lenA, ltag, Fmap, hist, paths);
}

// Round 6
// 78.583 us; speedup vs baseline: 2.2407x; 1.0378x over previous
//
#include <hip/hip_runtime.h>
#include <hip/hip_bf16.h>

#define TT 512
#define BB 64
#define KK 10
#define DD 1024
#define CL 32   // chunk length (steps per chunk)
#define NC 16   // number of chunks

typedef unsigned char uchar;
typedef short bf16x8 __attribute__((ext_vector_type(8)));
typedef float f32x4 __attribute__((ext_vector_type(4)));

__device__ __forceinline__ unsigned f2bf(float f) {  // RNE f32 -> bf16 bits
    unsigned u = __float_as_uint(f);
    return (u + 0x7FFFu + ((u >> 16) & 1u)) >> 16;
}

__device__ __forceinline__ float max10(const float* r) {
    float m0 = fmaxf(r[0], r[1]), m1 = fmaxf(r[2], r[3]);
    float m2 = fmaxf(r[4], r[5]), m3 = fmaxf(r[6], r[7]);
    float m4 = fmaxf(r[8], r[9]);
    m0 = fmaxf(m0, m1); m2 = fmaxf(m2, m3); m0 = fmaxf(m0, m2);
    return fmaxf(m0, m4);
}

__device__ __forceinline__ float lse10(const float* r) {
    const float m = max10(r);
    float s0 = __expf(r[0] - m) + __expf(r[1] - m);
    float s1 = __expf(r[2] - m) + __expf(r[3] - m);
    float s2 = __expf(r[4] - m) + __expf(r[5] - m);
    float s3 = __expf(r[6] - m) + __expf(r[7] - m);
    float s4 = __expf(r[8] - m) + __expf(r[9] - m);
    return m + __logf(((s0 + s1) + (s2 + s3)) + s4);
}

// ---------------- Kernel A: emissions via MFMA + lengths --------------------
// blocks 0..255: 128 rows (8 waves x one 16x16 tile, K=1024). B-fragments are
// register-resident (phase double-buffered from LDS) -> inner loop has NO LDS.
// block 256: lengths per batch + zero loss slot.
__global__ __launch_bounds__(512) void k_emissions(
    const int* __restrict__ words, const float* __restrict__ wf,
    const float* __restrict__ W, const float* __restrict__ bias,
    float* __restrict__ em, int* __restrict__ lenArr, float* loss_slot) {
    const int tid = threadIdx.x;
    if (blockIdx.x == 256) {
        __shared__ int cnt[8][64];
        const int b = tid & 63, seg = tid >> 6;
        int c = 0;
        for (int t = seg; t < TT; t += 8) c += (words[t * BB + b] != 0) ? 1 : 0;
        cnt[seg][b] = c;
        __syncthreads();
        if (tid < 64) {
            int s = 0;
            #pragma unroll
            for (int g = 0; g < 8; ++g) s += cnt[g][tid];
            lenArr[tid] = s;
        }
        if (tid == 0) *loss_slot = 0.f;
        return;
    }

    // B-fragment table: Bfrag[ks][lane] = 8 bf16 of W[ks*32 + (lane>>4)*8 + p][lane&15]
    __shared__ uint4 Bfrag[32][64];  // 32 KB
    for (int idx = tid; idx < 32 * 64; idx += 512) {
        const int ks = idx >> 6, l = idx & 63;
        const int col = l & 15, kg = l >> 4;
        unsigned u[4];
        #pragma unroll
        for (int p = 0; p < 4; ++p) {
            unsigned lo = 0, hi = 0;
            if (col < KK) {
                const int k0 = ks * 32 + kg * 8 + p * 2;
                lo = f2bf(W[(size_t)k0 * KK + col]);
                hi = f2bf(W[(size_t)(k0 + 1) * KK + col]);
            }
            u[p] = lo | (hi << 16);
        }
        Bfrag[ks][l] = make_uint4(u[0], u[1], u[2], u[3]);
    }
    __syncthreads();

    const int wave = tid >> 6, lane = tid & 63;
    const int arow = lane & 15;      // A row within tile (== C col)
    const int kg   = lane >> 4;      // k-group (and C row-group)
    const int row0 = blockIdx.x * 128 + wave * 16;
    const float* ap = wf + (size_t)(row0 + arow) * DD + kg * 8;
    const float bk = bias[arow < KK ? arow : 0];

    f32x4 acc = {0.f, 0.f, 0.f, 0.f};
    float4 fa[4], fb[4];
    #pragma unroll
    for (int p = 0; p < 4; ++p) {
        fa[p] = *reinterpret_cast<const float4*>(ap + p * 32);
        fb[p] = *reinterpret_cast<const float4*>(ap + p * 32 + 4);
    }
    uint4 bcur[8], bnxt[8];
    #pragma unroll
    for (int q = 0; q < 8; ++q) bcur[q] = Bfrag[q][lane];

    #pragma unroll
    for (int ph = 0; ph < 4; ++ph) {
        if (ph < 3) {
            #pragma unroll
            for (int q = 0; q < 8; ++q) bnxt[q] = Bfrag[(ph + 1) * 8 + q][lane];
        }
        #pragma unroll
        for (int q = 0; q < 8; ++q) {
            const int ks = ph * 8 + q;
            const int s = ks & 3;
            bf16x8 afr;
            afr[0] = (short)f2bf(fa[s].x); afr[1] = (short)f2bf(fa[s].y);
            afr[2] = (short)f2bf(fa[s].z); afr[3] = (short)f2bf(fa[s].w);
            afr[4] = (short)f2bf(fb[s].x); afr[5] = (short)f2bf(fb[s].y);
            afr[6] = (short)f2bf(fb[s].z); afr[7] = (short)f2bf(fb[s].w);
            if (ks < 28) {  // keep ~6-8 KB/wave in flight
                fa[s] = *reinterpret_cast<const float4*>(ap + (ks + 4) * 32);
                fb[s] = *reinterpret_cast<const float4*>(ap + (ks + 4) * 32 + 4);
            }
            union { uint4 u; bf16x8 v; } bu;
            bu.u = bcur[q];
            acc = __builtin_amdgcn_mfma_f32_16x16x32_bf16(afr, bu.v, acc, 0, 0, 0);
        }
        #pragma unroll
        for (int q = 0; q < 8; ++q) bcur[q] = bnxt[q];
    }
    // C layout: col = lane&15, row = (lane>>4)*4 + reg  [m89]
    if (arow < KK) {
        #pragma unroll
        for (int r = 0; r < 4; ++r)
            em[(size_t)(row0 + kg * 4 + r) * KK + arow] = acc[r] + bk;
    }
}

// ---------------- Kernel B: per-chunk 10x10 transfer matrices ---------------
// grid 2048: blockIdx = sem*1024 + b*16 + c; 128 threads, (i,j) = tid/10,tid%10.
__global__ __launch_bounds__(128) void k_chunk(
    const float* __restrict__ em, const float* __restrict__ trans,
    const int* __restrict__ lenArr, float* __restrict__ Mlse, float* __restrict__ Mmax) {
    int id = blockIdx.x;
    const bool mx = id >= 1024; id &= 1023;
    const int b = id >> 4, c = id & 15;
    const int len = lenArr[b];
    const int s_lo = c * CL + 1;
    const int s_hi = min(c * CL + CL, len - 1);
    const int ns = s_hi - s_lo + 1;
    if (ns <= 0) return;  // identity chunk: consumers skip it

    __shared__ float Ms[KK][12];
    __shared__ float eml[CL][KK];
    const int tid = threadIdx.x;
    for (int idx = tid; idx < CL * KK; idx += 128) {
        const int sl = idx / KK, j = idx % KK;
        const int s = s_lo + sl;
        eml[sl][j] = (s <= TT - 1) ? em[((size_t)s * BB + b) * KK + j] : 0.f;
    }
    const int i = tid / KK, j = tid % KK;
    const bool act = tid < KK * KK;
    float trc[KK];
    if (act) {
        #pragma unroll
        for (int k = 0; k < KK; ++k) trc[k] = trans[k * KK + j];
    }
    __syncthreads();
    float cur = 0.f;
    if (act) { cur = trans[i * KK + j] + eml[0][j]; Ms[i][j] = cur; }
    __syncthreads();
    for (int sl = 1; sl < ns; ++sl) {
        float row[KK];
        if (act) {
            #pragma unroll
            for (int k = 0; k < KK; ++k) row[k] = Ms[i][k] + trc[k];
        }
        __syncthreads();
        if (act) {
            cur = (mx ? max10(row) : lse10(row)) + eml[sl][j];
            Ms[i][j] = cur;
        }
        __syncthreads();
    }
    if (act) {
        float* out = mx ? Mmax : Mlse;
        out[((size_t)b * NC + c) * 100 + i * KK + j] = cur;
    }
}

// ---------------- Kernel C: merged fold + hist + backtrace + loss -----------
// grid 64 (one block per batch) x 1024 threads (16 waves).
// All chunk matrices + emissions live in LDS; no global latency chains.
__global__ __launch_bounds__(1024) void k_crf(
    const int* __restrict__ tags, const float* __restrict__ em,
    const float* __restrict__ startv, const float* __restrict__ endv,
    const float* __restrict__ trans, const int* __restrict__ lenArr,
    const float* __restrict__ Mlse, const float* __restrict__ Mmax,
    int* __restrict__ paths, float* __restrict__ loss_slot) {
    const int b = blockIdx.x;
    const int tid = threadIdx.x;
    const int wv = tid >> 6, lane = tid & 63;
    const int len = lenArr[b];

    __shared__ float Ml[NC][100];      // 6.4 KB
    __shared__ float Mm[NC][100];      // 6.4 KB
    __shared__ float eml[NC][CL][KK];  // 20.5 KB  (s = c*32+1+sl)
    __shared__ float ub[NC][KK];
    __shared__ uchar hl[NC][CL * KK];  // 5.1 KB
    __shared__ int   Fl[NC][KK];
    __shared__ int   vt[NC + 1];
    __shared__ float em0[KK];
    __shared__ float red[2];           // denom, numer

    for (int idx = tid; idx < NC * 100; idx += 1024) {
        Ml[idx / 100][idx % 100] = Mlse[(size_t)b * NC * 100 + idx];
        Mm[idx / 100][idx % 100] = Mmax[(size_t)b * NC * 100 + idx];
    }
    for (int idx = tid; idx < NC * CL * KK; idx += 1024) {
        const int c = idx / (CL * KK), r = idx % (CL * KK);
        const int sl = r / KK, j = r % KK;
        const int s = c * CL + 1 + sl;
        eml[c][sl][j] = (s <= TT - 1) ? em[((size_t)s * BB + b) * KK + j] : 0.f;
    }
    if (tid < KK) em0[tid] = em[(size_t)b * KK + tid];
    __syncthreads();

    if (wv == 0) {  // max-plus fold -> boundary vectors + last tag
        float v[KK];
        #pragma unroll
        for (int i = 0; i < KK; ++i) v[i] = startv[i] + em0[i];
        for (int c = 0; c < NC; ++c) {
            if (lane < KK) ub[c][lane] = v[lane];
            const int s_hi = min(c * CL + CL, len - 1);
            if (s_hi >= c * CL + 1) {
                float nv = 0.f;
                if (lane < KK) {
                    float r[KK];
                    #pragma unroll
                    for (int k = 0; k < KK; ++k) r[k] = v[k] + Mm[c][k * KK + lane];
                    nv = max10(r);
                }
                #pragma unroll
                for (int i = 0; i < KK; ++i) v[i] = __shfl(nv, i);
            }
        }
        float best = v[0] + endv[0];
        int bi = 0;
        #pragma unroll
        for (int i = 1; i < KK; ++i) {
            const float x = v[i] + endv[i];
            if (x > best) { best = x; bi = i; }
        }
        if (lane == 0) vt[NC] = bi;
    } else if (wv == 1) {  // LSE fold -> denominator
        float v[KK];
        #pragma unroll
        for (int i = 0; i < KK; ++i) v[i] = startv[i] + em0[i];
        for (int c = 0; c < NC; ++c) {
            const int s_hi = min(c * CL + CL, len - 1);
            if (s_hi >= c * CL + 1) {
                float nv = 0.f;
                if (lane < KK) {
                    float r[KK];
                    #pragma unroll
                    for (int k = 0; k < KK; ++k) r[k] = v[k] + Ml[c][k * KK + lane];
                    nv = lse10(r);
                }
                #pragma unroll
                for (int i = 0; i < KK; ++i) v[i] = __shfl(nv, i);
            }
        }
        float r[KK];
        #pragma unroll
        for (int i = 0; i < KK; ++i) r[i] = v[i] + endv[i];
        if (lane == 0) red[0] = lse10(r);
    } else if (wv == 2) {  // gold-path numerator
        float part = 0.f;
        for (int t = 1 + lane; t < len; t += 64) {
            const int tp = tags[(t - 1) * BB + b];
            const int tc = tags[t * BB + b];
            part += trans[tp * KK + tc] + eml[(t - 1) >> 5][(t - 1) & 31][tc];
        }
        #pragma unroll
        for (int off = 32; off >= 1; off >>= 1) part += __shfl_xor(part, off);
        if (lane == 0) {
            const int t0 = tags[b];
            const int te = tags[(len - 1) * BB + b];
            red[1] = part + startv[t0] + em0[t0] + endv[te];
        }
    }
    __syncthreads();

    // per-chunk Viterbi re-run from exact boundary vector (wave c owns chunk c)
    {
        const int c = wv;
        const int s_hi = min(c * CL + CL, len - 1);
        const int ns = s_hi - (c * CL + 1) + 1;
        if (ns > 0) {
            float trc[KK];
            if (lane < KK) {
                #pragma unroll
                for (int i = 0; i < KK; ++i) trc[i] = trans[i * KK + lane];
            }
            float s[KK];
            #pragma unroll
            for (int i = 0; i < KK; ++i) s[i] = ub[c][i];
            for (int sl = 0; sl < ns; ++sl) {
                float best = s[0] + trc[0];
                int bi = 0;
                #pragma unroll
                for (int i = 1; i < KK; ++i) {
                    const float x = s[i] + trc[i];
                    if (x > best) { best = x; bi = i; }
                }
                float snew = 0.f;
                if (lane < KK) {
                    snew = best + eml[c][sl][lane];
                    hl[c][sl * KK + lane] = (uchar)bi;
                }
                #pragma unroll
                for (int i = 0; i < KK; ++i) s[i] = __shfl(snew, i);
            }
            if (lane < KK) {  // compose chunk's backtrace map
                int cur = lane;
                for (int sl = ns - 1; sl >= 0; --sl) cur = hl[c][sl * KK + cur];
                Fl[c][lane] = cur;
            }
        }
    }
    __syncthreads();

    if (tid == 0) {  // boundary-tag fold + loss
        int cur = vt[NC];
        for (int c = NC - 1; c >= 0; --c) {
            const int s_hi = min(c * CL + CL, len - 1);
            if (s_hi >= c * CL + 1) cur = Fl[c][cur];
            vt[c] = cur;
        }
        atomicAdd(loss_slot, red[0] - red[1]);
    }
    __syncthreads();

    // emit: wave w writes path slice [32w, 32w+31]
    const int t0 = wv * CL;
    if (lane < CL) {
        const int t = t0 + lane;
        if (t >= len) paths[t * BB + b] = 0;
    }
    if (lane == 0) {
        const int a = min(t0 + CL, len - 1);
        if (a >= t0) {
            int cur = vt[wv + 1];  // = path[a]
            for (int t = a; t >= t0; --t) {
                if (t <= t0 + CL - 1) paths[t * BB + b] = cur;
                if (t > t0) cur = (int)hl[wv][(t - t0 - 1) * KK + cur];
            }
        }
    }
}

extern "C" void kernel_launch(void* const* d_in, const int* in_sizes, int n_in,
                              void* d_out, int out_size, void* d_ws, size_t ws_size,
                              hipStream_t stream) {
    const int*   words  = (const int*)d_in[0];
    const int*   tags   = (const int*)d_in[1];
    const float* wf     = (const float*)d_in[2];
    const float* W      = (const float*)d_in[3];
    const float* bias   = (const float*)d_in[4];
    const float* startv = (const float*)d_in[5];
    const float* endv   = (const float*)d_in[6];
    const float* trans  = (const float*)d_in[7];

    float* em   = (float*)d_ws;                       // 512*64*10 floats
    float* Mlse = em + 327680;                        // 64*16*100
    float* Mmax = Mlse + 102400;                      // 64*16*100
    int*   lenA = (int*)(Mmax + 102400);              // 64

    int*   paths     = (int*)d_out;                   // (T,B) int32 values
    float* loss_slot = ((float*)d_out) + TT * BB;     // scalar f32

    k_emissions<<<257, 512, 0, stream>>>(words, wf, W, bias, em, lenA, loss_slot);
    k_chunk<<<2048, 128, 0, stream>>>(em, trans, lenA, Mlse, Mmax);
    k_crf<<<64, 1024, 0, stream>>>(tags, em, startv, endv, trans, lenA,
                                   Mlse, Mmax, paths, loss_slot);
}